// Round 6
// baseline (66266.724 us; speedup 1.0000x reference)
//
#include <hip/hip_runtime.h>

// ---------------------------------------------------------------------------
// ResRNN: sequential gated residual RNN, B=64, T=2048, D=32, H=256 (fp32).
//
// R6: row-group interleaving (C-slice pipelining) over the R5 exchange.
//  * R1-R5 post-mortem: inter-wg hop latency is pinned ~3.2-4.4us regardless
//    of protocol (fences, relaxed atomics, summaries, direct polls) -- it is
//    fabric/LLC latency under poll contention. So stop attacking the hop;
//    amortize it: each of 16 RNN wgs (one per 16-col slice) processes ALL 4
//    row-groups, phase-interleaved. While rg0's exchange is in flight the
//    wave computes rg1..rg3 -> first poll of a phase absorbs the stall,
//    the rest are ready. Weight slice in LDS shared by all rgs (89 KB).
//  * Exchange = R5's proven tagged payload ((t+1)<<16 | bf16, sc0 sc1,
//    fire-and-forget) + ADVISORY hint dwords for cheap not-ready spinning.
//    Correctness rests ONLY on the tag-checked read (hint races -> retry).
//  * Skew bound (same induction as R5, extended): wg A enters super-step t+1
//    only after polling h3(t) from every wg B => B passed its phase-4 h2
//    polls of step t => B completed phase-5 of t-1 (consumed h1(t) into
//    registers) => h1 parity slot and ring slots are never overwritten while
//    readable. Rings 32-deep, out-wg back-pressure every 8 steps.
//  * 4 out-wgs (bid 16..19) compute out = h2@O1 + h3@O2 + bo per rg.
//  * Risk: ~490 VGPR peak (4-rg register state). Fallback if spilling: 2-rg.
// ---------------------------------------------------------------------------

#define T_LEN 2048
#define BATCH 64
#define DIM   32
#define HID   256
#define NRG   4
#define RING  32

typedef short    frag_ab __attribute__((ext_vector_type(8)));   // 8 x bf16
typedef float    frag_cd __attribute__((ext_vector_type(4)));   // 4 x f32
typedef float    float4v __attribute__((ext_vector_type(4)));
typedef unsigned uint4v  __attribute__((ext_vector_type(4)));

#define MFMA16(a, b, c) __builtin_amdgcn_mfma_f32_16x16x32_bf16((a), (b), (c), 0, 0, 0)

// LDS slot bases (1 slot = one K-tile of B-frags = 64 lanes * 16 B = 1 KB)
#define S_W1 0
#define S_U1 1
#define S_W2 9
#define S_U2 17
#define S_W3 25
#define S_U3 33
#define S_V3 41
#define S_G1 49   // 49..56 h1-part, 57..64 h2-part
#define S_G2 65   // 65..72 h1, 73..80 h2, 81..88 h3
#define NSLOT 89
#define LDS_BYTES (NSLOT * 64 * 16)   // 91,136 B

// workspace layout
#define H1_OFF   0
#define H1_SZ    (2 * BATCH * HID * 4)              // 128 KB (parity slots)
#define H2R_OFF  (H1_OFF + H1_SZ)
#define H2R_SZ   (RING * BATCH * HID * 4)           // 2 MB
#define H3R_OFF  (H2R_OFF + H2R_SZ)
#define H3R_SZ   (RING * BATCH * HID * 4)           // 2 MB
#define HINT_OFF (H3R_OFF + H3R_SZ)
#define HINT_DW  (3 * NRG * 16 * 16)                // [state][rg][prod] pad16
#define DONE_DW  (NRG * 16)
#define CTL_SZ   ((HINT_DW + DONE_DW) * 4)          // memset region

__device__ __forceinline__ unsigned short f2bf(float f) {
  unsigned u = __builtin_bit_cast(unsigned, f);
  u = (u + 0x7FFFu + ((u >> 16) & 1u)) >> 16;   // RNE
  return (unsigned short)u;
}

__device__ __forceinline__ float fast_tanh(float x) {
  x = fminf(fmaxf(x, -15.f), 15.f);
  float e = __expf(2.f * x);
  return (e - 1.f) / (e + 1.f);
}

__device__ __forceinline__ float fast_sigmoid(float x) {
  x = fminf(fmaxf(x, -30.f), 30.f);
  return 1.f / (1.f + __expf(-x));
}

// ---- LLC-visible memory ops (sc0 sc1) ----
__device__ __forceinline__ void st_sys_u32(unsigned* p, unsigned v) {
  asm volatile("global_store_dword %0, %1, off sc0 sc1" :: "v"(p), "v"(v) : "memory");
}
__device__ __forceinline__ unsigned ld_sys_u32(const unsigned* p) {
  unsigned r;
  asm volatile("global_load_dword %0, %1, off sc0 sc1\n\t"
               "s_waitcnt vmcnt(0)"
               : "=v"(r) : "v"(p) : "memory");
  return r;
}

// one-shot payload read: 16 x dwordx4 (sc0 sc1) pipelined, single vmcnt.
__device__ __forceinline__ void load16_sys(const unsigned* p, uint4v r[16]) {
  asm volatile(
      "global_load_dwordx4 %0, %16, off sc0 sc1\n\t"
      "global_load_dwordx4 %1, %16, off offset:16 sc0 sc1\n\t"
      "global_load_dwordx4 %2, %16, off offset:128 sc0 sc1\n\t"
      "global_load_dwordx4 %3, %16, off offset:144 sc0 sc1\n\t"
      "global_load_dwordx4 %4, %16, off offset:256 sc0 sc1\n\t"
      "global_load_dwordx4 %5, %16, off offset:272 sc0 sc1\n\t"
      "global_load_dwordx4 %6, %16, off offset:384 sc0 sc1\n\t"
      "global_load_dwordx4 %7, %16, off offset:400 sc0 sc1\n\t"
      "global_load_dwordx4 %8, %16, off offset:512 sc0 sc1\n\t"
      "global_load_dwordx4 %9, %16, off offset:528 sc0 sc1\n\t"
      "global_load_dwordx4 %10, %16, off offset:640 sc0 sc1\n\t"
      "global_load_dwordx4 %11, %16, off offset:656 sc0 sc1\n\t"
      "global_load_dwordx4 %12, %16, off offset:768 sc0 sc1\n\t"
      "global_load_dwordx4 %13, %16, off offset:784 sc0 sc1\n\t"
      "global_load_dwordx4 %14, %16, off offset:896 sc0 sc1\n\t"
      "global_load_dwordx4 %15, %16, off offset:912 sc0 sc1\n\t"
      "s_waitcnt vmcnt(0)"
      : "=v"(r[0]), "=v"(r[1]), "=v"(r[2]), "=v"(r[3]),
        "=v"(r[4]), "=v"(r[5]), "=v"(r[6]), "=v"(r[7]),
        "=v"(r[8]), "=v"(r[9]), "=v"(r[10]), "=v"(r[11]),
        "=v"(r[12]), "=v"(r[13]), "=v"(r[14]), "=v"(r[15])
      : "v"(p)
      : "memory");
}

__device__ __forceinline__ bool unpack_check(const uint4v r[16], unsigned tag16, frag_ab* a) {
  bool ok = true;
  #pragma unroll
  for (int kt = 0; kt < 8; ++kt) {
    #pragma unroll
    for (int j = 0; j < 8; ++j) {
      unsigned w = r[kt * 2 + (j >> 2)][j & 3];
      ok &= ((w >> 16) == tag16);
      a[kt][j] = (short)w;
    }
  }
  return ok;
}

// optimistic tag-checked read; on miss, cheap hint spin (hints are ADVISORY:
// monotonic, fire-and-forget; correctness is solely the tag check)
__device__ __forceinline__ void read_state_hint(const unsigned* p, const unsigned* hb,
                                                unsigned tag, int lane, frag_ab* a) {
  const unsigned* hp = hb + (size_t)(lane & 15) * 16;
  for (;;) {
    uint4v r[16];
    load16_sys(p, r);
    if (__all(unpack_check(r, tag, a))) return;
    while (!__all(ld_sys_u32(hp) >= tag)) {}
  }
}

// publish 4 tagged payload words (rows rr at stride HID), fire-and-forget
__device__ __forceinline__ void publish4(unsigned* pp, unsigned tag16, const float* v) {
  #pragma unroll
  for (int rr = 0; rr < 4; ++rr)
    st_sys_u32(pp + (size_t)rr * HID, (tag16 << 16) | (unsigned)f2bf(v[rr]));
}

__global__ void __launch_bounds__(64, 1)
resrnn_kernel(const float* __restrict__ x,
              const float* __restrict__ W1, const float* __restrict__ U1, const float* __restrict__ b1,
              const float* __restrict__ W2, const float* __restrict__ U2, const float* __restrict__ b2,
              const float* __restrict__ W3, const float* __restrict__ U3, const float* __restrict__ V3,
              const float* __restrict__ b3,
              const float* __restrict__ G1, const float* __restrict__ bg1,
              const float* __restrict__ G2, const float* __restrict__ bg2,
              const float* __restrict__ O1, const float* __restrict__ O2, const float* __restrict__ bo,
              float* __restrict__ out,
              unsigned* __restrict__ h1buf,   // [2][BATCH][HID] tagged
              unsigned* __restrict__ h2r,     // [RING][BATCH][HID] tagged
              unsigned* __restrict__ h3r,     // [RING][BATCH][HID] tagged
              unsigned* __restrict__ hints,   // [3][NRG][16] pad16, advisory
              unsigned* __restrict__ done)    // [NRG] pad16, monotonic
{
  extern __shared__ char smem[];
  frag_ab* wf = (frag_ab*)smem;

  const int lane = (int)threadIdx.x;   // block = 1 wave of 64
  const int quad = lane >> 4;
  const int nn   = lane & 15;
  const int bid  = (int)blockIdx.x;

  const size_t BH = (size_t)BATCH * HID;

  if (bid < 16) {
    // ---------------- RNN workgroup: col-slice sl, ALL 4 row-groups --------
    const int sl = bid;
    const int colbase = sl * 16;

    // ---- stage slice weights into LDS as bf16 B-fragments ----
    {
      const float* mats[9] = { W1, U1, W2, U2, W3, U3, V3, G1, G2 };
      const int    nkt[9]  = { 1, 8, 8, 8, 8, 8, 8, 16, 24 };
      int slot = 0;
      for (int m = 0; m < 9; ++m) {
        const float* W = mats[m];
        for (int kt = 0; kt < nkt[m]; ++kt) {
          frag_ab f;
          #pragma unroll
          for (int j = 0; j < 8; ++j) {
            int k = kt * 32 + quad * 8 + j;
            f[j] = (short)f2bf(W[(size_t)k * HID + colbase + nn]);
          }
          wf[slot * 64 + lane] = f;
          ++slot;
        }
      }
    }

    const float b1l  = b1[colbase + nn];
    const float b2l  = b2[colbase + nn];
    const float b3l  = b3[colbase + nn];
    const float bg1l = bg1[colbase + nn];
    const float bg2l = bg2[colbase + nn];

    const frag_ab zf = {0,0,0,0,0,0,0,0};
    frag_ab a1n[NRG][8], a3o[NRG][8];
    float h2l[NRG][4], h3l[NRG][4], z1l[NRG][4], z2l[NRG][4];
    frag_cd p2a[NRG], p2b[NRG], pg1[NRG], pg2[NRG];
    #pragma unroll
    for (int g = 0; g < NRG; ++g) {
      #pragma unroll
      for (int i = 0; i < 8; ++i) { a1n[g][i] = zf; a3o[g][i] = zf; }
      #pragma unroll
      for (int rr = 0; rr < 4; ++rr) {
        h2l[g][rr] = 0.f; h3l[g][rr] = 0.f; z1l[g][rr] = 1.f; z2l[g][rr] = 1.f;
      }
    }

    // ---- prologue: h1(0) per rg, publish tag1, gather, p2acc ----
    #pragma unroll
    for (int g = 0; g < NRG; ++g) {
      frag_cd p = {0.f,0.f,0.f,0.f};
      const float* xp = x + ((size_t)(g * 16 + nn) * T_LEN) * DIM + quad * 8;
      float4v xa = *(const float4v*)xp;
      float4v xb = *(const float4v*)(xp + 4);
      frag_ab xf;
      #pragma unroll
      for (int j = 0; j < 4; ++j) { xf[j] = (short)f2bf(xa[j]); xf[4 + j] = (short)f2bf(xb[j]); }
      p = MFMA16(xf, wf[S_W1 * 64 + lane], p);
      float v[4];
      #pragma unroll
      for (int rr = 0; rr < 4; ++rr) v[rr] = fast_tanh(p[rr] + b1l);
      publish4(h1buf + ((size_t)(g * 16 + quad * 4)) * HID + colbase + nn, 1u, v);
      if (lane == 0) st_sys_u32(hints + ((size_t)(0 * NRG + g) * 16 + sl) * 16, 1u);
    }
    #pragma unroll
    for (int g = 0; g < NRG; ++g) {
      read_state_hint(h1buf + ((size_t)(g * 16 + nn)) * HID + quad * 8,
                      hints + (size_t)(0 * NRG + g) * 256, 1u, lane, a1n[g]);
      p2a[g] = (frag_cd){0.f,0.f,0.f,0.f};
      p2b[g] = (frag_cd){0.f,0.f,0.f,0.f};
      #pragma unroll
      for (int kt = 0; kt < 4; ++kt) p2a[g] = MFMA16(a1n[g][kt], wf[(S_W2 + kt) * 64 + lane], p2a[g]);
      #pragma unroll
      for (int kt = 4; kt < 8; ++kt) p2b[g] = MFMA16(a1n[g][kt], wf[(S_W2 + kt) * 64 + lane], p2b[g]);
    }

    for (int t = 0; t < T_LEN; ++t) {
      const unsigned tag  = (unsigned)(t + 1);
      const int      slot = t & (RING - 1);
      const int      par  = (t + 1) & 1;

      // amortized ring back-pressure (covers slots t..t+7)
      if (t >= RING && (t & 7) == 0) {
        const unsigned need = (unsigned)(t - 24);
        #pragma unroll
        for (int g = 0; g < NRG; ++g)
          while (ld_sys_u32(done + g * 16) < need) {}
      }

      // ---- phase 1: h2(t) update + publish, all rgs ----
      #pragma unroll
      for (int g = 0; g < NRG; ++g) {
        #pragma unroll
        for (int rr = 0; rr < 4; ++rr) {
          float c = fast_tanh(p2a[g][rr] + p2b[g][rr] + b2l);
          h2l[g][rr] = z1l[g][rr] * c + (1.f - z1l[g][rr]) * h2l[g][rr];
        }
        publish4(h2r + ((size_t)slot * BATCH + g * 16 + quad * 4) * HID + colbase + nn,
                 tag, h2l[g]);
        if (lane == 0) st_sys_u32(hints + ((size_t)(1 * NRG + g) * 16 + sl) * 16, tag);
      }

      // ---- phase 2: h1(t+1) lookahead compute + publish ----
      if (t + 1 < T_LEN) {
        #pragma unroll
        for (int g = 0; g < NRG; ++g) {
          frag_cd p = {0.f,0.f,0.f,0.f};
          const float* xp = x + ((size_t)(g * 16 + nn) * T_LEN + (t + 1)) * DIM + quad * 8;
          float4v xa = *(const float4v*)xp;
          float4v xb = *(const float4v*)(xp + 4);
          frag_ab xf;
          #pragma unroll
          for (int j = 0; j < 4; ++j) { xf[j] = (short)f2bf(xa[j]); xf[4 + j] = (short)f2bf(xb[j]); }
          p = MFMA16(xf, wf[S_W1 * 64 + lane], p);
          #pragma unroll
          for (int kt = 0; kt < 8; ++kt) p = MFMA16(a1n[g][kt], wf[(S_U1 + kt) * 64 + lane], p);
          float v[4];
          #pragma unroll
          for (int rr = 0; rr < 4; ++rr) v[rr] = fast_tanh(p[rr] + b1l);
          publish4(h1buf + (size_t)par * BH + ((size_t)(g * 16 + quad * 4)) * HID + colbase + nn,
                   tag + 1u, v);
          if (lane == 0) st_sys_u32(hints + ((size_t)(0 * NRG + g) * 16 + sl) * 16, tag + 1u);
        }
      }

      // ---- phase 3: gate h1-parts (cover the h2 hop) ----
      #pragma unroll
      for (int g = 0; g < NRG; ++g) {
        pg1[g] = (frag_cd){0.f,0.f,0.f,0.f};
        pg2[g] = (frag_cd){0.f,0.f,0.f,0.f};
        #pragma unroll
        for (int kt = 0; kt < 8; ++kt) pg1[g] = MFMA16(a1n[g][kt], wf[(S_G1 + kt) * 64 + lane], pg1[g]);
        #pragma unroll
        for (int kt = 0; kt < 8; ++kt) pg2[g] = MFMA16(a1n[g][kt], wf[(S_G2 + kt) * 64 + lane], pg2[g]);
      }

      // ---- phase 4: per rg: poll h2 -> h3 compute+publish; gate h2-parts; U2 ----
      #pragma unroll
      for (int g = 0; g < NRG; ++g) {
        frag_ab a2[8];
        read_state_hint(h2r + ((size_t)slot * BATCH + g * 16 + nn) * HID + quad * 8,
                        hints + (size_t)(1 * NRG + g) * 256, tag, lane, a2);
        frag_cd p3 = {0.f,0.f,0.f,0.f};
        #pragma unroll
        for (int kt = 0; kt < 8; ++kt) p3 = MFMA16(a3o[g][kt], wf[(S_U3 + kt) * 64 + lane], p3);
        #pragma unroll
        for (int kt = 0; kt < 8; ++kt) p3 = MFMA16(a1n[g][kt], wf[(S_V3 + kt) * 64 + lane], p3);
        #pragma unroll
        for (int kt = 0; kt < 8; ++kt) p3 = MFMA16(a2[kt], wf[(S_W3 + kt) * 64 + lane], p3);
        #pragma unroll
        for (int rr = 0; rr < 4; ++rr) {
          float c = fast_tanh(p3[rr] + b3l);
          h3l[g][rr] = z2l[g][rr] * c + (1.f - z2l[g][rr]) * h3l[g][rr];
        }
        publish4(h3r + ((size_t)slot * BATCH + g * 16 + quad * 4) * HID + colbase + nn,
                 tag, h3l[g]);
        if (lane == 0) st_sys_u32(hints + ((size_t)(2 * NRG + g) * 16 + sl) * 16, tag);
        #pragma unroll
        for (int kt = 0; kt < 8; ++kt) pg1[g] = MFMA16(a2[kt], wf[(S_G1 + 8 + kt) * 64 + lane], pg1[g]);
        #pragma unroll
        for (int kt = 0; kt < 8; ++kt) pg2[g] = MFMA16(a2[kt], wf[(S_G2 + 8 + kt) * 64 + lane], pg2[g]);
        p2a[g] = (frag_cd){0.f,0.f,0.f,0.f};
        p2b[g] = (frag_cd){0.f,0.f,0.f,0.f};
        #pragma unroll
        for (int kt = 0; kt < 4; ++kt) p2a[g] = MFMA16(a2[kt], wf[(S_U2 + kt) * 64 + lane], p2a[g]);
        #pragma unroll
        for (int kt = 4; kt < 8; ++kt) p2b[g] = MFMA16(a2[kt], wf[(S_U2 + kt) * 64 + lane], p2b[g]);
      }

      // ---- phase 5: poll h1(t+1); accumulate W2@h1(t+1) ----
      if (t + 1 < T_LEN) {
        #pragma unroll
        for (int g = 0; g < NRG; ++g) {
          read_state_hint(h1buf + (size_t)par * BH + ((size_t)(g * 16 + nn)) * HID + quad * 8,
                          hints + (size_t)(0 * NRG + g) * 256, tag + 1u, lane, a1n[g]);
          #pragma unroll
          for (int kt = 0; kt < 4; ++kt) p2a[g] = MFMA16(a1n[g][kt], wf[(S_W2 + kt) * 64 + lane], p2a[g]);
          #pragma unroll
          for (int kt = 4; kt < 8; ++kt) p2b[g] = MFMA16(a1n[g][kt], wf[(S_W2 + kt) * 64 + lane], p2b[g]);
        }
      }

      // ---- phase 6: poll h3(t); gate h3-part; gates ----
      #pragma unroll
      for (int g = 0; g < NRG; ++g) {
        read_state_hint(h3r + ((size_t)slot * BATCH + g * 16 + nn) * HID + quad * 8,
                        hints + (size_t)(2 * NRG + g) * 256, tag, lane, a3o[g]);
        #pragma unroll
        for (int kt = 0; kt < 8; ++kt) pg2[g] = MFMA16(a3o[g][kt], wf[(S_G2 + 16 + kt) * 64 + lane], pg2[g]);
        #pragma unroll
        for (int rr = 0; rr < 4; ++rr) {
          float z1n = fast_sigmoid(pg1[g][rr] + bg1l);
          float z2n = fast_sigmoid(pg2[g][rr] + bg2l);
          z1l[g][rr] = z1n * z2n;
          z2l[g][rr] = z2n;
        }
      }
    }
  } else {
    // --------------------- output-projection workgroup ---------------------
    const int rg = bid - 16;
    {
      const float* mats[2] = { O1, O2 };
      for (int m = 0; m < 2; ++m)
        for (int nt = 0; nt < 2; ++nt)
          for (int kt = 0; kt < 8; ++kt) {
            frag_ab f;
            #pragma unroll
            for (int j = 0; j < 8; ++j) {
              int k = kt * 32 + quad * 8 + j;
              f[j] = (short)f2bf(mats[m][(size_t)k * DIM + nt * 16 + nn]);
            }
            wf[(m * 16 + nt * 8 + kt) * 64 + lane] = f;
          }
    }
    const float bo0 = bo[nn];
    const float bo1 = bo[16 + nn];

    for (int t = 0; t < T_LEN; ++t) {
      const unsigned tag  = (unsigned)(t + 1);
      const int      slot = t & (RING - 1);

      frag_ab a2[8], a3[8];
      read_state_hint(h2r + ((size_t)slot * BATCH + rg * 16 + nn) * HID + quad * 8,
                      hints + (size_t)(1 * NRG + rg) * 256, tag, lane, a2);
      read_state_hint(h3r + ((size_t)slot * BATCH + rg * 16 + nn) * HID + quad * 8,
                      hints + (size_t)(2 * NRG + rg) * 256, tag, lane, a3);

      frag_cd o0 = {0.f,0.f,0.f,0.f}, o1 = {0.f,0.f,0.f,0.f};
      #pragma unroll
      for (int kt = 0; kt < 8; ++kt) {
        o0 = MFMA16(a2[kt], wf[(0 * 16 + 0 * 8 + kt) * 64 + lane], o0);
        o1 = MFMA16(a2[kt], wf[(0 * 16 + 1 * 8 + kt) * 64 + lane], o1);
        o0 = MFMA16(a3[kt], wf[(1 * 16 + 0 * 8 + kt) * 64 + lane], o0);
        o1 = MFMA16(a3[kt], wf[(1 * 16 + 1 * 8 + kt) * 64 + lane], o1);
      }
      #pragma unroll
      for (int rr = 0; rr < 4; ++rr) {
        float* op = out + ((size_t)(rg * 16 + quad * 4 + rr) * T_LEN + t) * DIM;
        op[nn]      = o0[rr] + bo0;
        op[16 + nn] = o1[rr] + bo1;
      }
      if (lane == 0) st_sys_u32(done + rg * 16, tag);
    }
  }
}

extern "C" void kernel_launch(void* const* d_in, const int* in_sizes, int n_in,
                              void* d_out, int out_size, void* d_ws, size_t ws_size,
                              hipStream_t stream)
{
  (void)in_sizes; (void)n_in; (void)out_size; (void)ws_size;

  const float* x   = (const float*)d_in[0];
  const float* W1  = (const float*)d_in[1];
  const float* U1  = (const float*)d_in[2];
  const float* b1  = (const float*)d_in[3];
  const float* W2  = (const float*)d_in[4];
  const float* U2  = (const float*)d_in[5];
  const float* b2  = (const float*)d_in[6];
  const float* W3  = (const float*)d_in[7];
  const float* U3  = (const float*)d_in[8];
  const float* V3  = (const float*)d_in[9];
  const float* b3  = (const float*)d_in[10];
  const float* G1  = (const float*)d_in[11];
  const float* bg1 = (const float*)d_in[12];
  const float* G2  = (const float*)d_in[13];
  const float* bg2 = (const float*)d_in[14];
  const float* O1  = (const float*)d_in[15];
  const float* O2  = (const float*)d_in[16];
  const float* bo  = (const float*)d_in[17];

  char* ws = (char*)d_ws;
  unsigned* h1buf = (unsigned*)(ws + H1_OFF);
  unsigned* h2r   = (unsigned*)(ws + H2R_OFF);
  unsigned* h3r   = (unsigned*)(ws + H3R_OFF);
  unsigned* hints = (unsigned*)(ws + HINT_OFF);
  unsigned* done  = hints + HINT_DW;

  // hints + done must start at 0 (monotonic >= checks; ws poisoned 0xAA).
  // Tagged payload buffers need no init (poison tag never matches <= 2049).
  hipMemsetAsync(hints, 0, CTL_SZ, stream);

  (void)hipFuncSetAttribute((const void*)resrnn_kernel,
                            hipFuncAttributeMaxDynamicSharedMemorySize, LDS_BYTES);

  resrnn_kernel<<<dim3(20), dim3(64), LDS_BYTES, stream>>>(
      x, W1, U1, b1, W2, U2, b2, W3, U3, V3, b3,
      G1, bg1, G2, bg2, O1, O2, bo,
      (float*)d_out, h1buf, h2r, h3r, hints, done);
}

// Round 7
// 15059.694 us; speedup vs baseline: 4.4003x; 4.4003x over previous
//
#include <hip/hip_runtime.h>

// ---------------------------------------------------------------------------
// ResRNN: sequential gated residual RNN, B=64, T=2048, D=32, H=256 (fp32).
//
// R7 = R5 base (proven 13.8ms) + sample-poll hybrid exchange.
//  * R6 lesson: rg-interleave cannot reduce hops (rgs already concurrent in
//    separate wgs); it only trades pollers for VGPR spills (256-cap, 1.8GB
//    scratch fetch). Reverted.
//  * Hop theory: consumers' continuous 16KB/256-line payload polls contend
//    with producers' stores TO THE SAME LINES at the LLC -> store visibility
//    delayed -> more polling (hop ~3.4us vs ~0.3us raw RT).
//  * Fix: producers stay fire-and-forget (last program-order store = row 15
//    of the rg block). Consumers spin on a 1KB SAMPLE (row 15 only, 1
//    dwordx4/lane, 16 lines, covers all 16 producers' last stores), then
//    read the 16KB payload once and tag-verify. Sample is ADVISORY; the
//    tag-checked payload read remains the sole correctness mechanism
//    (out-of-order store visibility just causes a retry).
//  * h1 poll optimistic-first (published a phase earlier, usually ready);
//    h2/h3 sample-first. Out-wg + back-pressure spins s_sleep-paced.
//  * Topology/numerics = R5: 64 RNN wgs (4 rg x 16 col-slices, weights in
//    89KB LDS), 4 out-wgs, 2-hop critical cycle with h1 lookahead.
// ---------------------------------------------------------------------------

#define T_LEN 2048
#define BATCH 64
#define DIM   32
#define HID   256
#define NRG   4
#define RING  32

typedef short    frag_ab __attribute__((ext_vector_type(8)));   // 8 x bf16
typedef float    frag_cd __attribute__((ext_vector_type(4)));   // 4 x f32
typedef float    float4v __attribute__((ext_vector_type(4)));
typedef unsigned uint4v  __attribute__((ext_vector_type(4)));

#define MFMA16(a, b, c) __builtin_amdgcn_mfma_f32_16x16x32_bf16((a), (b), (c), 0, 0, 0)

// LDS slot bases (1 slot = one K-tile of B-frags = 64 lanes * 16 B = 1 KB)
#define S_W1 0
#define S_U1 1
#define S_W2 9
#define S_U2 17
#define S_W3 25
#define S_U3 33
#define S_V3 41
#define S_G1 49   // 49..56 h1-part, 57..64 h2-part
#define S_G2 65   // 65..72 h1, 73..80 h2, 81..88 h3
#define NSLOT 89
#define LDS_BYTES (NSLOT * 64 * 16)   // 91,136 B

// workspace layout
#define H1_OFF   0
#define H1_SZ    (2 * BATCH * HID * 4)              // 128 KB (parity slots)
#define H2R_OFF  (H1_OFF + H1_SZ)
#define H2R_SZ   (RING * BATCH * HID * 4)           // 2 MB
#define H3R_OFF  (H2R_OFF + H2R_SZ)
#define H3R_SZ   (RING * BATCH * HID * 4)           // 2 MB
#define CTL_OFF  (H3R_OFF + H3R_SZ)
#define CTL_SZ   (NRG * 16 * 4)                     // done[rg] pad 16 dw

__device__ __forceinline__ unsigned short f2bf(float f) {
  unsigned u = __builtin_bit_cast(unsigned, f);
  u = (u + 0x7FFFu + ((u >> 16) & 1u)) >> 16;   // RNE
  return (unsigned short)u;
}

__device__ __forceinline__ float fast_tanh(float x) {
  x = fminf(fmaxf(x, -15.f), 15.f);
  float e = __expf(2.f * x);
  return (e - 1.f) / (e + 1.f);
}

__device__ __forceinline__ float fast_sigmoid(float x) {
  x = fminf(fmaxf(x, -30.f), 30.f);
  return 1.f / (1.f + __expf(-x));
}

// ---- LLC-visible memory ops (sc0 sc1) ----
__device__ __forceinline__ void st_sys_u32(unsigned* p, unsigned v) {
  asm volatile("global_store_dword %0, %1, off sc0 sc1" :: "v"(p), "v"(v) : "memory");
}
__device__ __forceinline__ unsigned ld_sys_u32(const unsigned* p) {
  unsigned r;
  asm volatile("global_load_dword %0, %1, off sc0 sc1\n\t"
               "s_waitcnt vmcnt(0)"
               : "=v"(r) : "v"(p) : "memory");
  return r;
}
__device__ __forceinline__ uint4v ld_sys_u32x4(const unsigned* p) {
  uint4v r;
  asm volatile("global_load_dwordx4 %0, %1, off sc0 sc1\n\t"
               "s_waitcnt vmcnt(0)"
               : "=v"(r) : "v"(p) : "memory");
  return r;
}
__device__ __forceinline__ void nap() { asm volatile("s_sleep 2"); }

// one-shot payload read: 16 x dwordx4 (sc0 sc1) pipelined, single vmcnt.
__device__ __forceinline__ void load16_sys(const unsigned* p, uint4v r[16]) {
  asm volatile(
      "global_load_dwordx4 %0, %16, off sc0 sc1\n\t"
      "global_load_dwordx4 %1, %16, off offset:16 sc0 sc1\n\t"
      "global_load_dwordx4 %2, %16, off offset:128 sc0 sc1\n\t"
      "global_load_dwordx4 %3, %16, off offset:144 sc0 sc1\n\t"
      "global_load_dwordx4 %4, %16, off offset:256 sc0 sc1\n\t"
      "global_load_dwordx4 %5, %16, off offset:272 sc0 sc1\n\t"
      "global_load_dwordx4 %6, %16, off offset:384 sc0 sc1\n\t"
      "global_load_dwordx4 %7, %16, off offset:400 sc0 sc1\n\t"
      "global_load_dwordx4 %8, %16, off offset:512 sc0 sc1\n\t"
      "global_load_dwordx4 %9, %16, off offset:528 sc0 sc1\n\t"
      "global_load_dwordx4 %10, %16, off offset:640 sc0 sc1\n\t"
      "global_load_dwordx4 %11, %16, off offset:656 sc0 sc1\n\t"
      "global_load_dwordx4 %12, %16, off offset:768 sc0 sc1\n\t"
      "global_load_dwordx4 %13, %16, off offset:784 sc0 sc1\n\t"
      "global_load_dwordx4 %14, %16, off offset:896 sc0 sc1\n\t"
      "global_load_dwordx4 %15, %16, off offset:912 sc0 sc1\n\t"
      "s_waitcnt vmcnt(0)"
      : "=v"(r[0]), "=v"(r[1]), "=v"(r[2]), "=v"(r[3]),
        "=v"(r[4]), "=v"(r[5]), "=v"(r[6]), "=v"(r[7]),
        "=v"(r[8]), "=v"(r[9]), "=v"(r[10]), "=v"(r[11]),
        "=v"(r[12]), "=v"(r[13]), "=v"(r[14]), "=v"(r[15])
      : "v"(p)
      : "memory");
}

__device__ __forceinline__ bool unpack_check(const uint4v r[16], unsigned tag16, frag_ab* a) {
  bool ok = true;
  #pragma unroll
  for (int kt = 0; kt < 8; ++kt) {
    #pragma unroll
    for (int j = 0; j < 8; ++j) {
      unsigned w = r[kt * 2 + (j >> 2)][j & 3];
      ok &= ((w >> 16) == tag16);
      a[kt][j] = (short)w;
    }
  }
  return ok;
}

// advisory sample spin: row 15 of the rg block (each producer's LAST
// program-order store). rowbase = state base + (slot*BATCH + rg*16 + 15)*HID.
// 1 dwordx4/lane = 1KB = 16 lines per retry.
__device__ __forceinline__ void sample_wait(const unsigned* rowbase, unsigned tag,
                                            int lane, bool sleepy) {
  const unsigned* sp = rowbase + (size_t)lane * 4;
  for (;;) {
    uint4v s = ld_sys_u32x4(sp);
    bool ok = ((s[0] >> 16) == tag) & ((s[1] >> 16) == tag) &
              ((s[2] >> 16) == tag) & ((s[3] >> 16) == tag);
    if (__all(ok)) return;
    if (sleepy) nap();
  }
}

// sample-first read (for h2/h3: consumer usually arrives before data)
__device__ __forceinline__ void read_state_sf(const unsigned* p, const unsigned* rowbase,
                                              unsigned tag, int lane, frag_ab* a) {
  for (;;) {
    sample_wait(rowbase, tag, lane, false);
    uint4v r[16];
    load16_sys(p, r);
    if (__all(unpack_check(r, tag, a))) return;
  }
}

// optimistic-first read (for h1: data usually already visible)
__device__ __forceinline__ void read_state_of(const unsigned* p, const unsigned* rowbase,
                                              unsigned tag, int lane, frag_ab* a) {
  {
    uint4v r[16];
    load16_sys(p, r);
    if (__all(unpack_check(r, tag, a))) return;
  }
  for (;;) {
    sample_wait(rowbase, tag, lane, false);
    uint4v r[16];
    load16_sys(p, r);
    if (__all(unpack_check(r, tag, a))) return;
  }
}

// publish 4 tagged payload words (rows rr at stride HID), fire-and-forget.
// Highest row (quad3,rr=3 -> row 15 of the rg block) is the wave's last store.
__device__ __forceinline__ void publish4(unsigned* pp, unsigned tag16, const float* v) {
  #pragma unroll
  for (int rr = 0; rr < 4; ++rr)
    st_sys_u32(pp + (size_t)rr * HID, (tag16 << 16) | (unsigned)f2bf(v[rr]));
}

__global__ void __launch_bounds__(64, 1)
resrnn_kernel(const float* __restrict__ x,
              const float* __restrict__ W1, const float* __restrict__ U1, const float* __restrict__ b1,
              const float* __restrict__ W2, const float* __restrict__ U2, const float* __restrict__ b2,
              const float* __restrict__ W3, const float* __restrict__ U3, const float* __restrict__ V3,
              const float* __restrict__ b3,
              const float* __restrict__ G1, const float* __restrict__ bg1,
              const float* __restrict__ G2, const float* __restrict__ bg2,
              const float* __restrict__ O1, const float* __restrict__ O2, const float* __restrict__ bo,
              float* __restrict__ out,
              unsigned* __restrict__ h1buf,   // [2][BATCH][HID] tagged
              unsigned* __restrict__ h2r,     // [RING][BATCH][HID] tagged
              unsigned* __restrict__ h3r,     // [RING][BATCH][HID] tagged
              unsigned* __restrict__ done)    // [NRG] pad16, monotonic
{
  extern __shared__ char smem[];
  frag_ab* wf = (frag_ab*)smem;

  const int lane = (int)threadIdx.x;   // block = 1 wave of 64
  const int quad = lane >> 4;
  const int nn   = lane & 15;
  const int bid  = (int)blockIdx.x;

  if (bid < 64) {
    // ------------------------- RNN workgroup -------------------------
    const int rg = bid & 3;
    const int sl = bid >> 2;
    const int colbase = sl * 16;

    // ---- stage weights into LDS as bf16 B-fragments ----
    {
      const float* mats[9] = { W1, U1, W2, U2, W3, U3, V3, G1, G2 };
      const int    nkt[9]  = { 1, 8, 8, 8, 8, 8, 8, 16, 24 };
      int slot = 0;
      for (int m = 0; m < 9; ++m) {
        const float* W = mats[m];
        for (int kt = 0; kt < nkt[m]; ++kt) {
          frag_ab f;
          #pragma unroll
          for (int j = 0; j < 8; ++j) {
            int k = kt * 32 + quad * 8 + j;
            f[j] = (short)f2bf(W[(size_t)k * HID + colbase + nn]);
          }
          wf[slot * 64 + lane] = f;
          ++slot;
        }
      }
    }

    const float b1l  = b1[colbase + nn];
    const float b2l  = b2[colbase + nn];
    const float b3l  = b3[colbase + nn];
    const float bg1l = bg1[colbase + nn];
    const float bg2l = bg2[colbase + nn];

    const frag_ab zf = {0,0,0,0,0,0,0,0};
    frag_ab a1n[8], a3old[8];
    #pragma unroll
    for (int i = 0; i < 8; ++i) { a1n[i] = zf; a3old[i] = zf; }
    float h2l[4] = {0.f,0.f,0.f,0.f};
    float h3l[4] = {0.f,0.f,0.f,0.f};
    float z1l[4] = {1.f,1.f,1.f,1.f};
    float z2l[4] = {1.f,1.f,1.f,1.f};

    const float*    xrow  = x + (size_t)(rg * 16 + nn) * T_LEN * DIM + quad * 8;
    unsigned*       h1pub = h1buf + ((size_t)(rg * 16 + quad * 4)) * HID + colbase + nn;
    const unsigned* h1rd  = h1buf + ((size_t)(rg * 16 + nn)) * HID + quad * 8;
    const unsigned* h1smp = h1buf + ((size_t)(rg * 16 + 15)) * HID;
    const size_t    h1st  = (size_t)BATCH * HID;   // parity-slot stride (dwords)

    // ---- prologue: h1(0) = tanh(x(0)@W1 + b1), publish slot0 tag1 ----
    {
      frag_cd p = {0.f,0.f,0.f,0.f};
      float4v xa = *(const float4v*)xrow;
      float4v xb = *(const float4v*)(xrow + 4);
      frag_ab xf;
      #pragma unroll
      for (int j = 0; j < 4; ++j) { xf[j] = (short)f2bf(xa[j]); xf[4 + j] = (short)f2bf(xb[j]); }
      p = MFMA16(xf, wf[S_W1 * 64 + lane], p);
      float v[4];
      #pragma unroll
      for (int rr = 0; rr < 4; ++rr) v[rr] = fast_tanh(p[rr] + b1l);
      publish4(h1pub, 1u, v);
    }
    read_state_of(h1rd, h1smp, 1u, lane, a1n);      // a1n = h1(0)

    // p2acc = W2@h1(0) + U2@h2(-1=0)
    frag_cd p2a = {0.f,0.f,0.f,0.f}, p2b = {0.f,0.f,0.f,0.f};
    #pragma unroll
    for (int kt = 0; kt < 4; ++kt) p2a = MFMA16(a1n[kt], wf[(S_W2 + kt) * 64 + lane], p2a);
    #pragma unroll
    for (int kt = 4; kt < 8; ++kt) p2b = MFMA16(a1n[kt], wf[(S_W2 + kt) * 64 + lane], p2b);

    for (int t = 0; t < T_LEN; ++t) {
      const unsigned tag  = (unsigned)(t + 1);
      const int      slot = t & (RING - 1);
      const size_t   rowb2 = ((size_t)slot * BATCH + rg * 16) * HID;   // h2/h3 rg block base

      // amortized ring back-pressure: cover slots for steps t..t+7
      if (t >= RING && (t & 7) == 0) {
        const unsigned need = (unsigned)(t - RING + 8);
        while (ld_sys_u32(done + rg * 16) < need) { nap(); }
      }

      // ---- 1. h2(t) update + publish (p2acc ready, z1 from gates(t-1)) ----
      #pragma unroll
      for (int rr = 0; rr < 4; ++rr) {
        float c = fast_tanh(p2a[rr] + p2b[rr] + b2l);
        h2l[rr] = z1l[rr] * c + (1.f - z1l[rr]) * h2l[rr];
      }
      publish4(h2r + rowb2 + (size_t)(quad * 4) * HID + colbase + nn, tag, h2l);

      // ---- 2. h1 lookahead: h1(t+1) = tanh(x(t+1)@W1 + U1@h1(t) + b1) ----
      if (t + 1 < T_LEN) {
        frag_cd p = {0.f,0.f,0.f,0.f};
        const float* xp = xrow + (size_t)(t + 1) * DIM;
        float4v xa = *(const float4v*)xp;
        float4v xb = *(const float4v*)(xp + 4);
        frag_ab xf;
        #pragma unroll
        for (int j = 0; j < 4; ++j) { xf[j] = (short)f2bf(xa[j]); xf[4 + j] = (short)f2bf(xb[j]); }
        p = MFMA16(xf, wf[S_W1 * 64 + lane], p);
        #pragma unroll
        for (int kt = 0; kt < 8; ++kt) p = MFMA16(a1n[kt], wf[(S_U1 + kt) * 64 + lane], p);
        float v[4];
        #pragma unroll
        for (int rr = 0; rr < 4; ++rr) v[rr] = fast_tanh(p[rr] + b1l);
        publish4(h1pub + ((size_t)((t + 1) & 1)) * h1st, tag + 1u, v);
      }

      // ---- 3. precompute (indep of h2(t), h3(t)) ----
      frag_cd p3u = {0.f,0.f,0.f,0.f}, pg1a = {0.f,0.f,0.f,0.f}, pg2a = {0.f,0.f,0.f,0.f};
      #pragma unroll
      for (int kt = 0; kt < 8; ++kt) p3u = MFMA16(a3old[kt], wf[(S_U3 + kt) * 64 + lane], p3u);
      #pragma unroll
      for (int kt = 0; kt < 8; ++kt) p3u = MFMA16(a1n[kt], wf[(S_V3 + kt) * 64 + lane], p3u);
      #pragma unroll
      for (int kt = 0; kt < 8; ++kt) pg1a = MFMA16(a1n[kt], wf[(S_G1 + kt) * 64 + lane], pg1a);
      #pragma unroll
      for (int kt = 0; kt < 8; ++kt) pg2a = MFMA16(a1n[kt], wf[(S_G2 + kt) * 64 + lane], pg2a);

      // ---- 4. poll h2(t) full (sample-first) ----
      frag_ab a2[8];
      read_state_sf(h2r + rowb2 + (size_t)nn * HID + quad * 8,
                    h2r + rowb2 + (size_t)15 * HID, tag, lane, a2);

      // ---- 5. h3(t) update + publish ----
      {
        frag_cd p3 = p3u;
        #pragma unroll
        for (int kt = 0; kt < 8; ++kt) p3 = MFMA16(a2[kt], wf[(S_W3 + kt) * 64 + lane], p3);
        #pragma unroll
        for (int rr = 0; rr < 4; ++rr) {
          float c = fast_tanh(p3[rr] + b3l);
          h3l[rr] = z2l[rr] * c + (1.f - z2l[rr]) * h3l[rr];
        }
        publish4(h3r + rowb2 + (size_t)(quad * 4) * HID + colbase + nn, tag, h3l);
      }

      // ---- 6. precompute next-iter p2acc + gate h2-parts; poll h1(t+1) ----
      frag_cd pg1b = {0.f,0.f,0.f,0.f}, pg2b = {0.f,0.f,0.f,0.f};
      #pragma unroll
      for (int kt = 0; kt < 8; ++kt) pg1b = MFMA16(a2[kt], wf[(S_G1 + 8 + kt) * 64 + lane], pg1b);
      #pragma unroll
      for (int kt = 0; kt < 8; ++kt) pg2b = MFMA16(a2[kt], wf[(S_G2 + 8 + kt) * 64 + lane], pg2b);
      p2a = (frag_cd){0.f,0.f,0.f,0.f};
      p2b = (frag_cd){0.f,0.f,0.f,0.f};
      #pragma unroll
      for (int kt = 0; kt < 4; ++kt) p2a = MFMA16(a2[kt], wf[(S_U2 + kt) * 64 + lane], p2a);
      #pragma unroll
      for (int kt = 4; kt < 8; ++kt) p2b = MFMA16(a2[kt], wf[(S_U2 + kt) * 64 + lane], p2b);
      if (t + 1 < T_LEN) {
        const size_t po = ((size_t)((t + 1) & 1)) * h1st;
        read_state_of(h1rd + po, h1smp + po, tag + 1u, lane, a1n);   // a1n = h1(t+1)
        #pragma unroll
        for (int kt = 0; kt < 4; ++kt) p2a = MFMA16(a1n[kt], wf[(S_W2 + kt) * 64 + lane], p2a);
        #pragma unroll
        for (int kt = 4; kt < 8; ++kt) p2b = MFMA16(a1n[kt], wf[(S_W2 + kt) * 64 + lane], p2b);
      }

      // ---- 7. poll h3(t) full (sample-first) ----
      read_state_sf(h3r + rowb2 + (size_t)nn * HID + quad * 8,
                    h3r + rowb2 + (size_t)15 * HID, tag, lane, a3old);

      // ---- 8. gates(t) ----
      frag_cd pg2c = {0.f,0.f,0.f,0.f};
      #pragma unroll
      for (int kt = 0; kt < 8; ++kt) pg2c = MFMA16(a3old[kt], wf[(S_G2 + 16 + kt) * 64 + lane], pg2c);
      #pragma unroll
      for (int rr = 0; rr < 4; ++rr) {
        float z1n = fast_sigmoid(pg1a[rr] + pg1b[rr] + bg1l);
        float z2n = fast_sigmoid(pg2a[rr] + pg2b[rr] + pg2c[rr] + bg2l);
        z1l[rr] = z1n * z2n;
        z2l[rr] = z2n;
      }
    }
  } else {
    // --------------------- output-projection workgroup ---------------------
    const int rg = bid - 64;
    {
      const float* mats[2] = { O1, O2 };
      for (int m = 0; m < 2; ++m)
        for (int nt = 0; nt < 2; ++nt)
          for (int kt = 0; kt < 8; ++kt) {
            frag_ab f;
            #pragma unroll
            for (int j = 0; j < 8; ++j) {
              int k = kt * 32 + quad * 8 + j;
              f[j] = (short)f2bf(mats[m][(size_t)k * DIM + nt * 16 + nn]);
            }
            wf[(m * 16 + nt * 8 + kt) * 64 + lane] = f;
          }
    }
    const float bo0 = bo[nn];
    const float bo1 = bo[16 + nn];

    for (int t = 0; t < T_LEN; ++t) {
      const unsigned tag  = (unsigned)(t + 1);
      const int      slot = t & (RING - 1);
      const size_t   rowb = ((size_t)slot * BATCH + rg * 16) * HID;

      // sleepy sample spins (off critical path; minimize background polls)
      sample_wait(h2r + rowb + (size_t)15 * HID, tag, lane, true);
      sample_wait(h3r + rowb + (size_t)15 * HID, tag, lane, true);

      frag_ab a2[8], a3[8];
      for (;;) {
        uint4v r2[16], r3[16];
        load16_sys(h2r + rowb + (size_t)nn * HID + quad * 8, r2);
        load16_sys(h3r + rowb + (size_t)nn * HID + quad * 8, r3);
        bool ok = unpack_check(r2, tag, a2);
        ok &= unpack_check(r3, tag, a3);
        if (__all(ok)) break;
        nap();
      }

      frag_cd o0 = {0.f,0.f,0.f,0.f}, o1 = {0.f,0.f,0.f,0.f};
      #pragma unroll
      for (int kt = 0; kt < 8; ++kt) {
        o0 = MFMA16(a2[kt], wf[(0 * 16 + 0 * 8 + kt) * 64 + lane], o0);
        o1 = MFMA16(a2[kt], wf[(0 * 16 + 1 * 8 + kt) * 64 + lane], o1);
        o0 = MFMA16(a3[kt], wf[(1 * 16 + 0 * 8 + kt) * 64 + lane], o0);
        o1 = MFMA16(a3[kt], wf[(1 * 16 + 1 * 8 + kt) * 64 + lane], o1);
      }
      #pragma unroll
      for (int rr = 0; rr < 4; ++rr) {
        float* op = out + ((size_t)(rg * 16 + quad * 4 + rr) * T_LEN + t) * DIM;
        op[nn]      = o0[rr] + bo0;
        op[16 + nn] = o1[rr] + bo1;
      }
      // ring data consumed into registers -> free slot
      if (lane == 0) st_sys_u32(done + rg * 16, tag);
    }
  }
}

extern "C" void kernel_launch(void* const* d_in, const int* in_sizes, int n_in,
                              void* d_out, int out_size, void* d_ws, size_t ws_size,
                              hipStream_t stream)
{
  (void)in_sizes; (void)n_in; (void)out_size; (void)ws_size;

  const float* x   = (const float*)d_in[0];
  const float* W1  = (const float*)d_in[1];
  const float* U1  = (const float*)d_in[2];
  const float* b1  = (const float*)d_in[3];
  const float* W2  = (const float*)d_in[4];
  const float* U2  = (const float*)d_in[5];
  const float* b2  = (const float*)d_in[6];
  const float* W3  = (const float*)d_in[7];
  const float* U3  = (const float*)d_in[8];
  const float* V3  = (const float*)d_in[9];
  const float* b3  = (const float*)d_in[10];
  const float* G1  = (const float*)d_in[11];
  const float* bg1 = (const float*)d_in[12];
  const float* G2  = (const float*)d_in[13];
  const float* bg2 = (const float*)d_in[14];
  const float* O1  = (const float*)d_in[15];
  const float* O2  = (const float*)d_in[16];
  const float* bo  = (const float*)d_in[17];

  char* ws = (char*)d_ws;
  unsigned* h1buf = (unsigned*)(ws + H1_OFF);
  unsigned* h2r   = (unsigned*)(ws + H2R_OFF);
  unsigned* h3r   = (unsigned*)(ws + H3R_OFF);
  unsigned* done  = (unsigned*)(ws + CTL_OFF);

  // done[] must start at 0 (ws poisoned 0xAA). Tagged payload buffers need
  // no init (poison tag 0xAAAA never matches a real tag <= 2049).
  hipMemsetAsync(done, 0, CTL_SZ, stream);

  (void)hipFuncSetAttribute((const void*)resrnn_kernel,
                            hipFuncAttributeMaxDynamicSharedMemorySize, LDS_BYTES);

  resrnn_kernel<<<dim3(68), dim3(64), LDS_BYTES, stream>>>(
      x, W1, U1, b1, W2, U2, b2, W3, U3, V3, b3,
      G1, bg1, G2, bg2, O1, O2, bo,
      (float*)d_out, h1buf, h2r, h3r, done);
}